// Round 1
// baseline (328.928 us; speedup 1.0000x reference)
//
#include <hip/hip_runtime.h>

// Haar (db1) 2-D DWT, non-overlapping 2x2 block transform.
// Input:  (16, 3, 1024, 1024) fp32
// Output: 4 planes (cA, cH, cV, cD), each (16, 3, 512, 512) fp32, concat flat.
//
// Memory-bound: 192 MiB read + 192 MiB write. Each thread handles 4 output
// columns (8 input columns) of one output row: 2x float4 loads from each of
// the two input rows, 4x float4 coalesced stores (one per output plane).

#define IN_W   1024
#define IN_H   1024
#define IMG_IN (IN_H * IN_W)
#define OUT_W  512
#define OUT_H  512
#define IMG_OUT (OUT_H * OUT_W)
#define N_IMG  48                       // B*C = 16*3
#define PLANE  ((size_t)N_IMG * IMG_OUT) // elements per output plane

__global__ __launch_bounds__(256) void haar_dwt2_kernel(
    const float* __restrict__ x, float* __restrict__ out)
{
    int t = blockIdx.x * blockDim.x + threadIdx.x;

    int oxg  = t & 127;        // output column group: 4 cols each -> 128 groups/row
    int rest = t >> 7;
    int oy   = rest & 511;     // output row
    int img  = rest >> 9;      // (b,c) image index, 0..47

    const float* img_base = x + (size_t)img * IMG_IN;
    const float4* row0 = (const float4*)(img_base + (size_t)(2 * oy)     * IN_W) + oxg * 2;
    const float4* row1 = (const float4*)(img_base + (size_t)(2 * oy + 1) * IN_W) + oxg * 2;

    float4 a0 = row0[0];  // even row, input cols [8g .. 8g+3]
    float4 a1 = row0[1];  // even row, input cols [8g+4 .. 8g+7]
    float4 b0 = row1[0];  // odd row
    float4 b1 = row1[1];

    float4 cA, cH, cV, cD;

    // output col j: x00 = even-row even-col, x01 = even-row odd-col,
    //               x10 = odd-row even-col,  x11 = odd-row odd-col
    cA.x = (a0.x + a0.y + b0.x + b0.y) * 0.5f;
    cH.x = (a0.x + a0.y - b0.x - b0.y) * 0.5f;
    cV.x = (a0.x - a0.y + b0.x - b0.y) * 0.5f;
    cD.x = (a0.x - a0.y - b0.x + b0.y) * 0.5f;

    cA.y = (a0.z + a0.w + b0.z + b0.w) * 0.5f;
    cH.y = (a0.z + a0.w - b0.z - b0.w) * 0.5f;
    cV.y = (a0.z - a0.w + b0.z - b0.w) * 0.5f;
    cD.y = (a0.z - a0.w - b0.z + b0.w) * 0.5f;

    cA.z = (a1.x + a1.y + b1.x + b1.y) * 0.5f;
    cH.z = (a1.x + a1.y - b1.x - b1.y) * 0.5f;
    cV.z = (a1.x - a1.y + b1.x - b1.y) * 0.5f;
    cD.z = (a1.x - a1.y - b1.x + b1.y) * 0.5f;

    cA.w = (a1.z + a1.w + b1.z + b1.w) * 0.5f;
    cH.w = (a1.z + a1.w - b1.z - b1.w) * 0.5f;
    cV.w = (a1.z - a1.w + b1.z - b1.w) * 0.5f;
    cD.w = (a1.z - a1.w - b1.z + b1.w) * 0.5f;

    size_t o = (size_t)img * IMG_OUT + (size_t)oy * OUT_W + (size_t)oxg * 4;
    *(float4*)(out + 0 * PLANE + o) = cA;
    *(float4*)(out + 1 * PLANE + o) = cH;
    *(float4*)(out + 2 * PLANE + o) = cV;
    *(float4*)(out + 3 * PLANE + o) = cD;
}

extern "C" void kernel_launch(void* const* d_in, const int* in_sizes, int n_in,
                              void* d_out, int out_size, void* d_ws, size_t ws_size,
                              hipStream_t stream)
{
    const float* x = (const float*)d_in[0];
    float* out = (float*)d_out;

    // 48 images * 512 output rows * 128 col-groups = 3,145,728 threads
    int total_threads = N_IMG * OUT_H * 128;
    int block = 256;
    int grid = total_threads / block;  // 12288

    haar_dwt2_kernel<<<grid, block, 0, stream>>>(x, out);
}